// Round 2
// baseline (365.082 us; speedup 1.0000x reference)
//
#include <hip/hip_runtime.h>

// RSCA split into two kernels (d_ws >= 4MB) so each runs in its own regime:
//   A: pool_x  — pure HBM streaming reduce, x[128,8192,7,7] -> xpT[n][j] (4MB,
//      transposed for contiguous reads in B). 13 float4 loads in flight/thread,
//      grid 2048, ~6 waves/SIMD.
//   B: rsca_attn — all 4 scalar-embed MHAs + residuals. Inputs 8MB (L2-hot),
//      trans-pipe bound (5.4e8 exp2). Grid 512 x 512T = 16 waves/CU; XCD-
//      bijective swizzle for L2 write-merge; per-column minmax via wave shuffle;
//      coalesced 64B output flush through padded LDS obuf.
// Fallback: single fused kernel (round-1) if ws_size < 4MB.

constexpr int B_SEQ = 128;
constexpr int N_COL = 8192;
constexpr int HWP   = 49;

typedef float v2f __attribute__((ext_vector_type(2)));

#if __has_builtin(__builtin_elementwise_fma)
#define VFMA(a, b, c) __builtin_elementwise_fma((a), (b), (c))
#else
__device__ __forceinline__ v2f VFMA(v2f a, v2f b, v2f c) {
    v2f r; r.x = fmaf(a.x, b.x, c.x); r.y = fmaf(a.y, b.y, c.y); return r;
}
#endif

// ======================= Kernel A: pool x -> xpT =========================
constexpr int ANT = 256;
constexpr int ATC = 4;

__global__ __launch_bounds__(ANT, 6) void pool_x(
    const float* __restrict__ x, float* __restrict__ xpT)
{
    const int t   = threadIdx.x;
    const int n0  = blockIdx.x * ATC;
    const int ql  = t & 3;
    const int seg = t >> 2;

    for (int pass = 0; pass < 2; ++pass) {
        const int j = pass * 64 + seg;
        const float4* __restrict__ base =
            (const float4*)(x + ((size_t)j * N_COL + n0) * (size_t)HWP);
        float4 v[13];
        #pragma unroll
        for (int k = 0; k < 12; ++k) v[k] = base[ql + 4 * k];
        v[12] = base[48];

        float s0 = 0.f, s1 = 0.f, s2 = 0.f, s3 = 0.f;
        s0 += v[0].x + v[0].y + v[0].z + v[0].w;
        s0 += v[1].x + v[1].y + v[1].z + v[1].w;
        s0 += v[2].x + v[2].y + v[2].z + v[2].w;
        s1 += v[4].x + v[4].y + v[4].z + v[4].w;
        s1 += v[5].x + v[5].y + v[5].z + v[5].w;
        s2 += v[7].x + v[7].y + v[7].z + v[7].w;
        s2 += v[8].x + v[8].y + v[8].z + v[8].w;
        s3 += v[10].x + v[10].y + v[10].z + v[10].w;
        s3 += v[11].x + v[11].y + v[11].z + v[11].w;
        { const float sm = v[3].x + v[3].y + v[3].z + v[3].w;
          const float cr = (ql == 0) ? v[3].x : 0.0f;
          s0 += cr; s1 += sm - cr; }
        { const float sm = v[6].x + v[6].y + v[6].z + v[6].w;
          const float cr = (ql == 0) ? (v[6].x + v[6].y) : 0.0f;
          s1 += cr; s2 += sm - cr; }
        { const float sm = v[9].x + v[9].y + v[9].z + v[9].w;
          const float cr = (ql == 0) ? (v[9].x + v[9].y + v[9].z) : 0.0f;
          s2 += cr; s3 += sm - cr; }
        const float tail = v[12].x + v[12].y + v[12].z + v[12].w;

        s0 += __shfl_xor(s0, 1); s1 += __shfl_xor(s1, 1);
        s2 += __shfl_xor(s2, 1); s3 += __shfl_xor(s3, 1);
        s0 += __shfl_xor(s0, 2); s1 += __shfl_xor(s1, 2);
        s2 += __shfl_xor(s2, 2); s3 += __shfl_xor(s3, 2);
        float r = s0;
        r = (ql == 1) ? s1 : r;
        r = (ql == 2) ? s2 : r;
        r = (ql == 3) ? (s3 + tail) : r;
        const float mean = r * (1.0f / HWP);
        xpT[(size_t)(n0 + ql) * B_SEQ + j] = mean;
    }
}

// ======================= Kernel B: attention ============================
constexpr int BNT = 512;
constexpr int BTC = 16;    // columns per block
constexpr int OPAD = 17;   // obuf row stride (floats): 2-way max on writes

__global__ __launch_bounds__(BNT, 4) void rsca_attn(
    const float* __restrict__ xpT, const float* __restrict__ y,
    const float* __restrict__ pwq, const float* __restrict__ pwk,
    const float* __restrict__ pwv, const float* __restrict__ pbq,
    const float* __restrict__ pbk, const float* __restrict__ pbv,
    const float* __restrict__ pwo, const float* __restrict__ pbo,
    float* __restrict__ out)
{
    __shared__ float xv[BTC][B_SEQ];
    __shared__ float yv[BTC][B_SEQ];
    __shared__ float pmny[8][BTC], pmxy[8][BTC];
    __shared__ float pmnx[BTC], pmxx[BTC];
    __shared__ float obuf[2][B_SEQ * OPAD];

    const int t    = threadIdx.x;
    const int lane = t & 63;
    const int wv   = t >> 6;
    // bijective XCD swizzle (gridDim 512 % 8 == 0): consecutive column-groups
    // land on the same XCD -> L2 write-merge of 64B halves + y locality.
    const int cg = (blockIdx.x & 7) * ((int)gridDim.x >> 3) + (blockIdx.x >> 3);
    const int n0 = cg * BTC;

    const float wq = pwq[0], wk = pwk[0], wvv = pwv[0];
    const float bq = pbq[0], bk = pbk[0], bv = pbv[0];
    const float wo = pwo[0], bo = pbo[0];
    const float L2E = 1.4426950408889634f;
    const float wkL = wk * L2E, bkL = bk * L2E;
    const float alpha = wo * wvv;
    const float beta2 = 2.0f * (wo * bv + bo);

    // ---- stage xv from xpT (contiguous float4) + per-column minmax ----
    {
        const float4 v4 = *(const float4*)&xpT[(size_t)n0 * B_SEQ + t * 4];
        const int c  = t >> 5;          // wave covers cols {2wv, 2wv+1}, 32 lanes each
        const int j0 = (t & 31) * 4;
        *(float4*)&xv[c][j0] = v4;
        float mn = fminf(fminf(v4.x, v4.y), fminf(v4.z, v4.w));
        float mx = fmaxf(fmaxf(v4.x, v4.y), fmaxf(v4.z, v4.w));
        #pragma unroll
        for (int off = 1; off <= 16; off <<= 1) {
            mn = fminf(mn, __shfl_xor(mn, off));
            mx = fmaxf(mx, __shfl_xor(mx, off));
        }
        if ((lane & 31) == 0) { pmnx[c] = mn; pmxx[c] = mx; }   // full column done
    }
    // ---- stage yv (column gather, L2-resident) + wave-partial minmax ----
    {
        const int c  = t & 15;
        const int jb = t >> 4;          // 0..31
        float fy[4];
        #pragma unroll
        for (int r = 0; r < 4; ++r)
            fy[r] = y[(size_t)(jb + 32 * r) * N_COL + n0 + c];
        #pragma unroll
        for (int r = 0; r < 4; ++r)
            yv[c][jb + 32 * r] = fy[r];
        float mn = fminf(fminf(fy[0], fy[1]), fminf(fy[2], fy[3]));
        float mx = fmaxf(fmaxf(fy[0], fy[1]), fmaxf(fy[2], fy[3]));
        mn = fminf(mn, __shfl_xor(mn, 16)); mx = fmaxf(mx, __shfl_xor(mx, 16));
        mn = fminf(mn, __shfl_xor(mn, 32)); mx = fmaxf(mx, __shfl_xor(mx, 32));
        if (lane < 16) { pmny[wv][c] = mn; pmxy[wv][c] = mx; }
    }
    __syncthreads();

    const int ch = t >> 7;              // 0..3, wave-uniform
    const int i  = t & (B_SEQ - 1);

    #pragma unroll
    for (int cc = 0; cc < 4; ++cc) {
        const int c = ch * 4 + cc;      // wave-uniform -> LDS broadcast
        const float* __restrict__ vx = xv[c];
        const float* __restrict__ vy = yv[c];

        const float vxmn = pmnx[c], vxmx = pmxx[c];
        float vymn = pmny[0][c], vymx = pmxy[0][c];
        #pragma unroll
        for (int s = 1; s < 8; ++s) {
            vymn = fminf(vymn, pmny[s][c]);
            vymx = fmaxf(vymx, pmxy[s][c]);
        }
        const float axv = fmaf(vxmx, wkL, bkL), bxv = fmaf(vxmn, wkL, bkL);
        const float kxmx = fmaxf(axv, bxv), kxmn = fminf(axv, bxv);
        const float ayv = fmaf(vymx, wkL, bkL), byv = fmaf(vymn, wkL, bkL);
        const float kymx = fmaxf(ayv, byv), kymn = fminf(ayv, byv);

        const float xi = vx[i], yi = vy[i];
        const float qx = fmaf(xi, wq, bq), qy = fmaf(yi, wq, bq);
        const float nmsx = -(qx >= 0.f ? qx * kxmx : qx * kxmn);
        const float nmcy = -(qy >= 0.f ? qy * kxmx : qy * kxmn);
        const float nmsy = -(qy >= 0.f ? qy * kymx : qy * kymn);
        const float nmcx = -(qx >= 0.f ? qx * kymx : qx * kymn);

        // score*log2e = v*(q*wkL) + (q*bkL + nm)
        const float qxw = qx * wkL, qyw = qy * wkL;
        const v2f qxw2 = {qxw, qxw}, qyw2 = {qyw, qyw};
        const float csx = fmaf(qx, bkL, nmsx), ccy = fmaf(qy, bkL, nmcy);
        const float csy = fmaf(qy, bkL, nmsy), ccx = fmaf(qx, bkL, nmcx);
        const v2f csx2 = {csx, csx}, ccy2 = {ccy, ccy};
        const v2f csy2 = {csy, csy}, ccx2 = {ccx, ccx};

        v2f s0sx = {0.f, 0.f}, s1sx = {0.f, 0.f};
        v2f s0cy = {0.f, 0.f}, s1cy = {0.f, 0.f};
        v2f s0sy = {0.f, 0.f}, s1sy = {0.f, 0.f};
        v2f s0cx = {0.f, 0.f}, s1cx = {0.f, 0.f};

        for (int j0 = 0; j0 < B_SEQ; j0 += 8) {
            const float4 a0 = *(const float4*)&vx[j0];
            const float4 a1 = *(const float4*)&vx[j0 + 4];
            const float4 b0 = *(const float4*)&vy[j0];
            const float4 b1 = *(const float4*)&vy[j0 + 4];
            auto px2 = [&](float v0, float v1) {
                const v2f vvj = {v0, v1};
                v2f t1 = VFMA(qxw2, vvj, csx2);
                v2f e1; e1.x = __builtin_amdgcn_exp2f(t1.x);
                        e1.y = __builtin_amdgcn_exp2f(t1.y);
                s1sx = VFMA(e1, vvj, s1sx); s0sx += e1;
                v2f t2 = VFMA(qyw2, vvj, ccy2);
                v2f e2; e2.x = __builtin_amdgcn_exp2f(t2.x);
                        e2.y = __builtin_amdgcn_exp2f(t2.y);
                s1cy = VFMA(e2, vvj, s1cy); s0cy += e2;
            };
            auto py2 = [&](float v0, float v1) {
                const v2f vvj = {v0, v1};
                v2f t3 = VFMA(qyw2, vvj, csy2);
                v2f e3; e3.x = __builtin_amdgcn_exp2f(t3.x);
                        e3.y = __builtin_amdgcn_exp2f(t3.y);
                s1sy = VFMA(e3, vvj, s1sy); s0sy += e3;
                v2f t4 = VFMA(qxw2, vvj, ccx2);
                v2f e4; e4.x = __builtin_amdgcn_exp2f(t4.x);
                        e4.y = __builtin_amdgcn_exp2f(t4.y);
                s1cx = VFMA(e4, vvj, s1cx); s0cx += e4;
            };
            px2(a0.x, a0.y); px2(a0.z, a0.w); px2(a1.x, a1.y); px2(a1.z, a1.w);
            py2(b0.x, b0.y); py2(b0.z, b0.w); py2(b1.x, b1.y); py2(b1.z, b1.w);
        }
        const float S0sx = s0sx.x + s0sx.y, S1sx = s1sx.x + s1sx.y;
        const float S0cy = s0cy.x + s0cy.y, S1cy = s1cy.x + s1cy.y;
        const float S0sy = s0sy.x + s0sy.y, S1sy = s1sy.x + s1sy.y;
        const float S0cx = s0cx.x + s0cx.y, S1cx = s1cx.x + s1cx.y;
        const float mx_attn = S1sx * __builtin_amdgcn_rcpf(S0sx)
                            + S1cx * __builtin_amdgcn_rcpf(S0cx);
        const float my_attn = S1sy * __builtin_amdgcn_rcpf(S0sy)
                            + S1cy * __builtin_amdgcn_rcpf(S0cy);
        obuf[0][i * OPAD + c] = fmaf(alpha, mx_attn, beta2 + xi);
        obuf[1][i * OPAD + c] = fmaf(alpha, my_attn, beta2 + yi);
    }
    __syncthreads();

    // ---- coalesced flush: 64B row segments per (i,set) ----
    #pragma unroll
    for (int k = 0; k < 2; ++k) {
        const int fidx = t + k * BNT;           // 0..1023
        const int q   = fidx & 3;
        const int ii  = (fidx >> 2) & (B_SEQ - 1);
        const int set = fidx >> 9;
        const float* p = &obuf[set][ii * OPAD + q * 4];
        float4 val;
        val.x = p[0]; val.y = p[1]; val.z = p[2]; val.w = p[3];
        *(float4*)&out[(size_t)ii * (2 * N_COL) + (size_t)set * N_COL + n0 + q * 4] = val;
    }
}

// =================== Fallback: round-1 fused kernel ======================
constexpr int NT  = 256;
constexpr int TC  = 4;
constexpr int G   = 4;
constexpr int CPB = TC * G;
constexpr int VSTR = 132;
constexpr int OSTR = 21;

__global__ __launch_bounds__(NT, 2) void rsca_fused(
    const float* __restrict__ x, const float* __restrict__ y,
    const float* __restrict__ pwq, const float* __restrict__ pwk,
    const float* __restrict__ pwv, const float* __restrict__ pbq,
    const float* __restrict__ pbk, const float* __restrict__ pbv,
    const float* __restrict__ pwo, const float* __restrict__ pbo,
    float* __restrict__ out)
{
    __shared__ float vls[2][2][TC * VSTR];
    __shared__ float pmn[2][2][8][TC];
    __shared__ float pmx[2][2][8][TC];
    __shared__ float obuf[2][B_SEQ * OSTR];

    const int t       = threadIdx.x;
    const int bid     = blockIdx.x;
    const int colbase = bid * CPB;
    const int ql      = t & 3;
    const int seg     = t >> 2;
    const int lane    = t & 63;
    const int wid     = t >> 6;

    const float wq = pwq[0], wk = pwk[0], wv = pwv[0];
    const float bq = pbq[0], bk = pbk[0], bv = pbv[0];
    const float wo = pwo[0], bo = pbo[0];
    const float L2E = 1.4426950408889634f;
    const float wkL = wk * L2E, bkL = bk * L2E;
    const float alpha = wo * wv;
    const float beta2 = 2.0f * (wo * bv + bo);

    auto issue_pass = [&](int g, int p, float4 (&v)[13]) {
        const int j = p * 64 + seg;
        const float4* __restrict__ base =
            (const float4*)(x + ((size_t)j * N_COL + colbase + g * TC) * (size_t)HWP);
        #pragma unroll
        for (int k = 0; k < 12; ++k) v[k] = base[ql + 4 * k];
        v[12] = base[48];
    };

    auto reduce_pass = [&](int p, int nb, const float4 (&v)[13]) {
        float s0 = 0.f, s1 = 0.f, s2 = 0.f, s3 = 0.f;
        s0 += v[0].x + v[0].y + v[0].z + v[0].w;
        s0 += v[1].x + v[1].y + v[1].z + v[1].w;
        s0 += v[2].x + v[2].y + v[2].z + v[2].w;
        s1 += v[4].x + v[4].y + v[4].z + v[4].w;
        s1 += v[5].x + v[5].y + v[5].z + v[5].w;
        s2 += v[7].x + v[7].y + v[7].z + v[7].w;
        s2 += v[8].x + v[8].y + v[8].z + v[8].w;
        s3 += v[10].x + v[10].y + v[10].z + v[10].w;
        s3 += v[11].x + v[11].y + v[11].z + v[11].w;
        { const float sm = v[3].x + v[3].y + v[3].z + v[3].w;
          const float cr = (ql == 0) ? v[3].x : 0.0f;
          s0 += cr; s1 += sm - cr; }
        { const float sm = v[6].x + v[6].y + v[6].z + v[6].w;
          const float cr = (ql == 0) ? (v[6].x + v[6].y) : 0.0f;
          s1 += cr; s2 += sm - cr; }
        { const float sm = v[9].x + v[9].y + v[9].z + v[9].w;
          const float cr = (ql == 0) ? (v[9].x + v[9].y + v[9].z) : 0.0f;
          s2 += cr; s3 += sm - cr; }
        const float tail = v[12].x + v[12].y + v[12].z + v[12].w;
        s0 += __shfl_xor(s0, 1); s1 += __shfl_xor(s1, 1);
        s2 += __shfl_xor(s2, 1); s3 += __shfl_xor(s3, 1);
        s0 += __shfl_xor(s0, 2); s1 += __shfl_xor(s1, 2);
        s2 += __shfl_xor(s2, 2); s3 += __shfl_xor(s3, 2);
        float r = s0;
        r = (ql == 1) ? s1 : r;
        r = (ql == 2) ? s2 : r;
        r = (ql == 3) ? (s3 + tail) : r;
        const float mean = r * (1.0f / HWP);
        const int j = p * 64 + seg;
        vls[nb][0][ql * VSTR + j] = mean;
        float mn = mean, mx = mean;
        #pragma unroll
        for (int off = 4; off <= 32; off <<= 1) {
            mn = fminf(mn, __shfl_xor(mn, off));
            mx = fmaxf(mx, __shfl_xor(mx, off));
        }
        if (lane < 4) {
            pmn[nb][0][p * 4 + wid][ql] = mn;
            pmx[nb][0][p * 4 + wid][ql] = mx;
        }
    };

    auto stage_y = [&](int nb, float fy0, float fy1) {
        vls[nb][1][ql * VSTR + seg]      = fy0;
        vls[nb][1][ql * VSTR + seg + 64] = fy1;
        float mn = fminf(fy0, fy1), mx = fmaxf(fy0, fy1);
        #pragma unroll
        for (int off = 4; off <= 32; off <<= 1) {
            mn = fminf(mn, __shfl_xor(mn, off));
            mx = fmaxf(mx, __shfl_xor(mx, off));
        }
        if (lane < 4) {
            pmn[nb][1][wid][ql] = mn;
            pmx[nb][1][wid][ql] = mx;
        }
    };

    const int ch = t >> 7;
    const int i  = t & (B_SEQ - 1);

    auto attn = [&](int g, int cb, int cc) {
        const int c = ch * 2 + cc;
        const float* __restrict__ vx0 = &vls[cb][0][c * VSTR];
        const float* __restrict__ vy0 = &vls[cb][1][c * VSTR];

        float vxmn = pmn[cb][0][0][c], vxmx = pmx[cb][0][0][c];
        #pragma unroll
        for (int s = 1; s < 8; ++s) {
            vxmn = fminf(vxmn, pmn[cb][0][s][c]);
            vxmx = fmaxf(vxmx, pmx[cb][0][s][c]);
        }
        float vymn = pmn[cb][1][0][c], vymx = pmx[cb][1][0][c];
        #pragma unroll
        for (int s = 1; s < 4; ++s) {
            vymn = fminf(vymn, pmn[cb][1][s][c]);
            vymx = fmaxf(vymx, pmx[cb][1][s][c]);
        }
        const float axv = fmaf(vxmx, wkL, bkL), bxv = fmaf(vxmn, wkL, bkL);
        const float kxmx = fmaxf(axv, bxv), kxmn = fminf(axv, bxv);
        const float ayv = fmaf(vymx, wkL, bkL), byv = fmaf(vymn, wkL, bkL);
        const float kymx = fmaxf(ayv, byv), kymn = fminf(ayv, byv);

        const float xi = vx0[i], yi = vy0[i];
        const float qx = fmaf(xi, wq, bq), qy = fmaf(yi, wq, bq);
        const float nmsx = -(qx >= 0.f ? qx * kxmx : qx * kxmn);
        const float nmcy = -(qy >= 0.f ? qy * kxmx : qy * kxmn);
        const float nmsy = -(qy >= 0.f ? qy * kymx : qy * kymn);
        const float nmcx = -(qx >= 0.f ? qx * kymx : qx * kymn);

        const float qxw = qx * wkL, qyw = qy * wkL;
        const v2f qxw2 = {qxw, qxw}, qyw2 = {qyw, qyw};
        const float csx = fmaf(qx, bkL, nmsx), ccy = fmaf(qy, bkL, nmcy);
        const float csy = fmaf(qy, bkL, nmsy), ccx = fmaf(qx, bkL, nmcx);
        const v2f csx2 = {csx, csx}, ccy2 = {ccy, ccy};
        const v2f csy2 = {csy, csy}, ccx2 = {ccx, ccx};

        v2f s0sx = {0.f, 0.f}, s1sx = {0.f, 0.f};
        v2f s0cy = {0.f, 0.f}, s1cy = {0.f, 0.f};
        v2f s0sy = {0.f, 0.f}, s1sy = {0.f, 0.f};
        v2f s0cx = {0.f, 0.f}, s1cx = {0.f, 0.f};

        for (int j0 = 0; j0 < B_SEQ; j0 += 8) {
            const float4 a0 = *(const float4*)&vx0[j0];
            const float4 a1 = *(const float4*)&vx0[j0 + 4];
            const float4 b0 = *(const float4*)&vy0[j0];
            const float4 b1 = *(const float4*)&vy0[j0 + 4];
            auto px2 = [&](float v0, float v1) {
                const v2f vv = {v0, v1};
                v2f t1 = VFMA(qxw2, vv, csx2);
                v2f e1; e1.x = __builtin_amdgcn_exp2f(t1.x);
                        e1.y = __builtin_amdgcn_exp2f(t1.y);
                s1sx = VFMA(e1, vv, s1sx); s0sx += e1;
                v2f t2 = VFMA(qyw2, vv, ccy2);
                v2f e2; e2.x = __builtin_amdgcn_exp2f(t2.x);
                        e2.y = __builtin_amdgcn_exp2f(t2.y);
                s1cy = VFMA(e2, vv, s1cy); s0cy += e2;
            };
            auto py2 = [&](float v0, float v1) {
                const v2f vv = {v0, v1};
                v2f t3 = VFMA(qyw2, vv, csy2);
                v2f e3; e3.x = __builtin_amdgcn_exp2f(t3.x);
                        e3.y = __builtin_amdgcn_exp2f(t3.y);
                s1sy = VFMA(e3, vv, s1sy); s0sy += e3;
                v2f t4 = VFMA(qxw2, vv, ccx2);
                v2f e4; e4.x = __builtin_amdgcn_exp2f(t4.x);
                        e4.y = __builtin_amdgcn_exp2f(t4.y);
                s1cx = VFMA(e4, vv, s1cx); s0cx += e4;
            };
            px2(a0.x, a0.y); px2(a0.z, a0.w); px2(a1.x, a1.y); px2(a1.z, a1.w);
            py2(b0.x, b0.y); py2(b0.z, b0.w); py2(b1.x, b1.y); py2(b1.z, b1.w);
        }
        const float S0sx = s0sx.x + s0sx.y, S1sx = s1sx.x + s1sx.y;
        const float S0cy = s0cy.x + s0cy.y, S1cy = s1cy.x + s1cy.y;
        const float S0sy = s0sy.x + s0sy.y, S1sy = s1sy.x + s1sy.y;
        const float S0cx = s0cx.x + s0cx.y, S1cx = s1cx.x + s1cx.y;
        const float mx_attn = S1sx * __builtin_amdgcn_rcpf(S0sx)
                            + S1cx * __builtin_amdgcn_rcpf(S0cx);
        const float my_attn = S1sy * __builtin_amdgcn_rcpf(S0sy)
                            + S1cy * __builtin_amdgcn_rcpf(S0cy);
        obuf[0][i * OSTR + g * TC + c] = fmaf(alpha, mx_attn, beta2 + xi);
        obuf[1][i * OSTR + g * TC + c] = fmaf(alpha, my_attn, beta2 + yi);
    };

    float4 va[13], vb[13];
    float fy0, fy1;
    {
        const int col = colbase + ql;
        issue_pass(0, 0, va);
        issue_pass(0, 1, vb);
        fy0 = y[(size_t)seg * N_COL + col];
        fy1 = y[(size_t)(seg + 64) * N_COL + col];
        reduce_pass(0, 0, va);
        stage_y(0, fy0, fy1);
        reduce_pass(1, 0, vb);
    }
    __syncthreads();

    int cur = 0;
    for (int g = 0; g < G; ++g) {
        const int nb = cur ^ 1;
        const bool pf = (g + 1 < G);
        if (pf) {
            const int col = colbase + (g + 1) * TC + ql;
            issue_pass(g + 1, 0, va);
            fy0 = y[(size_t)seg * N_COL + col];
            fy1 = y[(size_t)(seg + 64) * N_COL + col];
        }
        attn(g, cur, 0);
        if (pf) {
            reduce_pass(0, nb, va);
            stage_y(nb, fy0, fy1);
            issue_pass(g + 1, 1, vb);
        }
        attn(g, cur, 1);
        if (pf) reduce_pass(1, nb, vb);
        __syncthreads();
        cur = nb;
    }

    #pragma unroll
    for (int idx = t; idx < 2 * B_SEQ * TC; idx += NT) {
        const int set = idx >> 9;
        const int rem = idx & 511;
        const int ii  = rem >> 2;
        const int q   = rem & 3;
        const float* p = &obuf[set][ii * OSTR + q * 4];
        float4 val;
        val.x = p[0]; val.y = p[1]; val.z = p[2]; val.w = p[3];
        *(float4*)&out[(size_t)ii * (2 * N_COL) + (size_t)set * N_COL + colbase + q * 4] = val;
    }
}

extern "C" void kernel_launch(void* const* d_in, const int* in_sizes, int n_in,
                              void* d_out, int out_size, void* d_ws, size_t ws_size,
                              hipStream_t stream) {
    const float* x   = (const float*)d_in[0];
    const float* y   = (const float*)d_in[1];
    const float* pwq = (const float*)d_in[2];
    const float* pwk = (const float*)d_in[3];
    const float* pwv = (const float*)d_in[4];
    const float* pbq = (const float*)d_in[5];
    const float* pbk = (const float*)d_in[6];
    const float* pbv = (const float*)d_in[7];
    const float* pwo = (const float*)d_in[8];
    const float* pbo = (const float*)d_in[9];
    float* out = (float*)d_out;

    const size_t need = (size_t)N_COL * B_SEQ * sizeof(float);   // 4 MB
    if (d_ws != nullptr && ws_size >= need) {
        float* xpT = (float*)d_ws;
        pool_x<<<dim3(N_COL / ATC), dim3(ANT), 0, stream>>>(x, xpT);
        rsca_attn<<<dim3(N_COL / BTC), dim3(BNT), 0, stream>>>(
            xpT, y, pwq, pwk, pwv, pbq, pbk, pbv, pwo, pbo, out);
    } else {
        rsca_fused<<<dim3(N_COL / CPB), dim3(NT), 0, stream>>>(
            x, y, pwq, pwk, pwv, pbq, pbk, pbv, pwo, pbo, out);
    }
}

// Round 3
// 322.925 us; speedup vs baseline: 1.1305x; 1.1305x over previous
//
#include <hip/hip_runtime.h>

// RSCA fully-fused, round-3. Structure = round-0 (grid 2048, TC=4 cols/block,
// inter-block pool/attn overlap) with:
//  - raw-only LDS (k-affine folded into per-query constants), v2f pk math
//  - register double-buffered attn j-loop (prefetch j0+8 before computing j0;
//    48 VALU + 16 trans body covers the ~120cy LDS latency)
//  - shuffle-based per-column min/max (no 32-way-conflict phase)
//  - padded LDS strides (132 / 5) for conflict-free staging + obuf
//  - obuf-staged float4 output + same-XCD contiguous-column swizzle so the 4
//    blocks sharing each 64B out line sit on one XCD (L2 write-merge)
//  - launch_bounds(256,5): VGPR<=102, 5 waves/SIMD, loads stay in flight

constexpr int B_SEQ = 128;
constexpr int N_COL = 8192;
constexpr int HWP   = 49;
constexpr int NT    = 256;
constexpr int TC    = 4;
constexpr int VSTR  = 132;   // value-array stride: c*132+j spreads banks, rows 16B-aligned
constexpr int OSTR  = 5;     // obuf stride: gcd(5,32)=1 -> conflict-free

typedef float v2f __attribute__((ext_vector_type(2)));

#if __has_builtin(__builtin_elementwise_fma)
#define VFMA(a, b, c) __builtin_elementwise_fma((a), (b), (c))
#else
__device__ __forceinline__ v2f VFMA(v2f a, v2f b, v2f c) {
    v2f r; r.x = fmaf(a.x, b.x, c.x); r.y = fmaf(a.y, b.y, c.y); return r;
}
#endif

__global__ __launch_bounds__(NT, 5) void rsca_fused(
    const float* __restrict__ x, const float* __restrict__ y,
    const float* __restrict__ pwq, const float* __restrict__ pwk,
    const float* __restrict__ pwv, const float* __restrict__ pbq,
    const float* __restrict__ pbk, const float* __restrict__ pbv,
    const float* __restrict__ pwo, const float* __restrict__ pbo,
    float* __restrict__ out)
{
    __shared__ float xv[TC * VSTR];          // raw pooled means, [c*VSTR + j]
    __shared__ float yv[TC * VSTR];          // raw y,           [c*VSTR + j]
    __shared__ float pmnx[8][TC], pmxx[8][TC];   // x partials: pass*4+wave
    __shared__ float pmny[4][TC], pmxy[4][TC];   // y partials: wave
    __shared__ float obuf[2][B_SEQ * OSTR];

    const int t    = threadIdx.x;
    const int bid  = blockIdx.x;
    // same-XCD contiguous columns: XCD k = bids {k, k+8, ...} -> column chunk k.
    // 4 adjacent cg's (sharing a 64B out line) are on one XCD -> L2 write-merge.
    const int cg = (bid & 7) * ((N_COL / TC) >> 3) + (bid >> 3);
    const int n0 = cg * TC;

    const int ql   = t & 3;
    const int seg  = t >> 2;
    const int lane = t & 63;
    const int wid  = t >> 6;

    const float wq = pwq[0], wk = pwk[0], wv = pwv[0];
    const float bq = pbq[0], bk = pbk[0], bv = pbv[0];
    const float wo = pwo[0], bo = pbo[0];
    const float L2E = 1.4426950408889634f;
    const float wkL = wk * L2E, bkL = bk * L2E;
    const float alpha = wo * wv;
    const float beta2 = 2.0f * (wo * bv + bo);

    // ---- stage y (raw) + wave-partial min/max ----
    {
        const int j = t >> 2, c = t & 3;
        const float fy0 = y[(size_t)j * N_COL + n0 + c];
        const float fy1 = y[(size_t)(j + 64) * N_COL + n0 + c];
        yv[c * VSTR + j]      = fy0;
        yv[c * VSTR + j + 64] = fy1;
        float mn = fminf(fy0, fy1), mx = fmaxf(fy0, fy1);
        #pragma unroll
        for (int off = 4; off <= 32; off <<= 1) {
            mn = fminf(mn, __shfl_xor(mn, off));
            mx = fmaxf(mx, __shfl_xor(mx, off));
        }
        if (lane < 4) { pmny[wid][lane] = mn; pmxy[wid][lane] = mx; }
    }

    // ---- pool x -> xv (raw means) + wave-partial min/max ----
    for (int pass = 0; pass < 2; ++pass) {
        const int j = pass * 64 + seg;
        const float4* __restrict__ base =
            (const float4*)(x + ((size_t)j * N_COL + n0) * (size_t)HWP);
        float4 v[13];
        #pragma unroll
        for (int k = 0; k < 12; ++k) v[k] = base[ql + 4 * k];
        v[12] = base[48];

        float s0 = 0.f, s1 = 0.f, s2 = 0.f, s3 = 0.f;
        s0 += v[0].x + v[0].y + v[0].z + v[0].w;
        s0 += v[1].x + v[1].y + v[1].z + v[1].w;
        s0 += v[2].x + v[2].y + v[2].z + v[2].w;
        s1 += v[4].x + v[4].y + v[4].z + v[4].w;
        s1 += v[5].x + v[5].y + v[5].z + v[5].w;
        s2 += v[7].x + v[7].y + v[7].z + v[7].w;
        s2 += v[8].x + v[8].y + v[8].z + v[8].w;
        s3 += v[10].x + v[10].y + v[10].z + v[10].w;
        s3 += v[11].x + v[11].y + v[11].z + v[11].w;
        { const float sm = v[3].x + v[3].y + v[3].z + v[3].w;
          const float cr = (ql == 0) ? v[3].x : 0.0f;
          s0 += cr; s1 += sm - cr; }
        { const float sm = v[6].x + v[6].y + v[6].z + v[6].w;
          const float cr = (ql == 0) ? (v[6].x + v[6].y) : 0.0f;
          s1 += cr; s2 += sm - cr; }
        { const float sm = v[9].x + v[9].y + v[9].z + v[9].w;
          const float cr = (ql == 0) ? (v[9].x + v[9].y + v[9].z) : 0.0f;
          s2 += cr; s3 += sm - cr; }
        const float tail = v[12].x + v[12].y + v[12].z + v[12].w;

        s0 += __shfl_xor(s0, 1); s1 += __shfl_xor(s1, 1);
        s2 += __shfl_xor(s2, 1); s3 += __shfl_xor(s3, 1);
        s0 += __shfl_xor(s0, 2); s1 += __shfl_xor(s1, 2);
        s2 += __shfl_xor(s2, 2); s3 += __shfl_xor(s3, 2);
        float r = s0;
        r = (ql == 1) ? s1 : r;
        r = (ql == 2) ? s2 : r;
        r = (ql == 3) ? (s3 + tail) : r;
        const float mean = r * (1.0f / HWP);
        xv[ql * VSTR + j] = mean;

        float mn = mean, mx = mean;
        #pragma unroll
        for (int off = 4; off <= 32; off <<= 1) {
            mn = fminf(mn, __shfl_xor(mn, off));
            mx = fmaxf(mx, __shfl_xor(mx, off));
        }
        if (lane < 4) {
            pmnx[pass * 4 + wid][lane] = mn;
            pmxx[pass * 4 + wid][lane] = mx;
        }
    }
    __syncthreads();

    // ---- attention: thread = (query i, half ch); 2 columns each ----
    const int i  = t & (B_SEQ - 1);
    const int ch = t >> 7;
    #pragma unroll
    for (int cc = 0; cc < 2; ++cc) {
        const int c = ch * 2 + cc;                  // wave-uniform -> LDS broadcast
        const float* __restrict__ vx = &xv[c * VSTR];
        const float* __restrict__ vy = &yv[c * VSTR];

        float vxmn = pmnx[0][c], vxmx = pmxx[0][c];
        #pragma unroll
        for (int s = 1; s < 8; ++s) {
            vxmn = fminf(vxmn, pmnx[s][c]);
            vxmx = fmaxf(vxmx, pmxx[s][c]);
        }
        float vymn = pmny[0][c], vymx = pmxy[0][c];
        #pragma unroll
        for (int s = 1; s < 4; ++s) {
            vymn = fminf(vymn, pmny[s][c]);
            vymx = fmaxf(vymx, pmxy[s][c]);
        }
        const float axv = fmaf(vxmx, wkL, bkL), bxv = fmaf(vxmn, wkL, bkL);
        const float kxmx = fmaxf(axv, bxv), kxmn = fminf(axv, bxv);
        const float ayv = fmaf(vymx, wkL, bkL), byv = fmaf(vymn, wkL, bkL);
        const float kymx = fmaxf(ayv, byv), kymn = fminf(ayv, byv);

        const float xi = vx[i], yi = vy[i];
        const float qx = fmaf(xi, wq, bq), qy = fmaf(yi, wq, bq);
        const float nmsx = -(qx >= 0.f ? qx * kxmx : qx * kxmn);
        const float nmcy = -(qy >= 0.f ? qy * kxmx : qy * kxmn);
        const float nmsy = -(qy >= 0.f ? qy * kymx : qy * kymn);
        const float nmcx = -(qx >= 0.f ? qx * kymx : qx * kymn);

        // score*log2e = v*(q*wkL) + (q*bkL + nm)
        const float qxw = qx * wkL, qyw = qy * wkL;
        const v2f qxw2 = {qxw, qxw}, qyw2 = {qyw, qyw};
        const float csx = fmaf(qx, bkL, nmsx), ccy = fmaf(qy, bkL, nmcy);
        const float csy = fmaf(qy, bkL, nmsy), ccx = fmaf(qx, bkL, nmcx);
        const v2f csx2 = {csx, csx}, ccy2 = {ccy, ccy};
        const v2f csy2 = {csy, csy}, ccx2 = {ccx, ccx};

        v2f s0sx = {0.f, 0.f}, s1sx = {0.f, 0.f};
        v2f s0cy = {0.f, 0.f}, s1cy = {0.f, 0.f};
        v2f s0sy = {0.f, 0.f}, s1sy = {0.f, 0.f};
        v2f s0cx = {0.f, 0.f}, s1cx = {0.f, 0.f};

        auto px2 = [&](float v0, float v1) {
            const v2f vvj = {v0, v1};
            v2f t1 = VFMA(qxw2, vvj, csx2);
            v2f e1; e1.x = __builtin_amdgcn_exp2f(t1.x);
                    e1.y = __builtin_amdgcn_exp2f(t1.y);
            s1sx = VFMA(e1, vvj, s1sx); s0sx += e1;
            v2f t2 = VFMA(qyw2, vvj, ccy2);
            v2f e2; e2.x = __builtin_amdgcn_exp2f(t2.x);
                    e2.y = __builtin_amdgcn_exp2f(t2.y);
            s1cy = VFMA(e2, vvj, s1cy); s0cy += e2;
        };
        auto py2 = [&](float v0, float v1) {
            const v2f vvj = {v0, v1};
            v2f t3 = VFMA(qyw2, vvj, csy2);
            v2f e3; e3.x = __builtin_amdgcn_exp2f(t3.x);
                    e3.y = __builtin_amdgcn_exp2f(t3.y);
            s1sy = VFMA(e3, vvj, s1sy); s0sy += e3;
            v2f t4 = VFMA(qxw2, vvj, ccx2);
            v2f e4; e4.x = __builtin_amdgcn_exp2f(t4.x);
                    e4.y = __builtin_amdgcn_exp2f(t4.y);
            s1cx = VFMA(e4, vvj, s1cx); s0cx += e4;
        };

        // register double-buffer: load j0+8 before computing j0's body
        float4 a0 = *(const float4*)&vx[0], a1 = *(const float4*)&vx[4];
        float4 b0 = *(const float4*)&vy[0], b1 = *(const float4*)&vy[4];
        for (int j0 = 0; j0 < B_SEQ; j0 += 8) {
            const int jn = (j0 + 8) & (B_SEQ - 1);     // wraps to 0 on last iter (dummy)
            float4 na0 = *(const float4*)&vx[jn];
            float4 na1 = *(const float4*)&vx[jn + 4];
            float4 nb0 = *(const float4*)&vy[jn];
            float4 nb1 = *(const float4*)&vy[jn + 4];

            px2(a0.x, a0.y); px2(a0.z, a0.w); px2(a1.x, a1.y); px2(a1.z, a1.w);
            py2(b0.x, b0.y); py2(b0.z, b0.w); py2(b1.x, b1.y); py2(b1.z, b1.w);

            a0 = na0; a1 = na1; b0 = nb0; b1 = nb1;
        }
        const float S0sx = s0sx.x + s0sx.y, S1sx = s1sx.x + s1sx.y;
        const float S0cy = s0cy.x + s0cy.y, S1cy = s1cy.x + s1cy.y;
        const float S0sy = s0sy.x + s0sy.y, S1sy = s1sy.x + s1sy.y;
        const float S0cx = s0cx.x + s0cx.y, S1cx = s1cx.x + s1cx.y;
        const float mx_attn = S1sx * __builtin_amdgcn_rcpf(S0sx)
                            + S1cx * __builtin_amdgcn_rcpf(S0cx);
        const float my_attn = S1sy * __builtin_amdgcn_rcpf(S0sy)
                            + S1cy * __builtin_amdgcn_rcpf(S0cy);
        obuf[0][i * OSTR + c] = fmaf(alpha, mx_attn, beta2 + xi);
        obuf[1][i * OSTR + c] = fmaf(alpha, my_attn, beta2 + yi);
    }
    __syncthreads();

    // ---- flush: one float4 per thread, 16B row segments (L2 merges 4 blocks
    // of the same XCD into 64B lines) ----
    {
        const int set = t >> 7;
        const int ii  = t & (B_SEQ - 1);
        const float* p = &obuf[set][ii * OSTR];
        float4 val;
        val.x = p[0]; val.y = p[1]; val.z = p[2]; val.w = p[3];
        *(float4*)&out[(size_t)ii * (2 * N_COL) + (size_t)set * N_COL + n0] = val;
    }
}

extern "C" void kernel_launch(void* const* d_in, const int* in_sizes, int n_in,
                              void* d_out, int out_size, void* d_ws, size_t ws_size,
                              hipStream_t stream) {
    const float* x   = (const float*)d_in[0];
    const float* y   = (const float*)d_in[1];
    const float* pwq = (const float*)d_in[2];
    const float* pwk = (const float*)d_in[3];
    const float* pwv = (const float*)d_in[4];
    const float* pbq = (const float*)d_in[5];
    const float* pbk = (const float*)d_in[6];
    const float* pbv = (const float*)d_in[7];
    const float* pwo = (const float*)d_in[8];
    const float* pbo = (const float*)d_in[9];
    float* out = (float*)d_out;

    rsca_fused<<<dim3(N_COL / TC), dim3(NT), 0, stream>>>(
        x, y, pwq, pwk, pwv, pbq, pbk, pbv, pwo, pbo, out);
}